// Round 2
// baseline (2189.949 us; speedup 1.0000x reference)
//
#include <hip/hip_runtime.h>

#define H 64
#define CIN 32
#define TWOH 128
#define NGRAPH 64

// ---------------- input GEMM: x0[N,64] = x[N,32] @ Win + bin ----------------
extern "C" __global__ void __launch_bounds__(256) k_input_gemm(
    const float* __restrict__ x, const float* __restrict__ Win,
    const float* __restrict__ bin, float* __restrict__ x0, int N)
{
    __shared__ float Wl[CIN * H]; // 8 KB
    for (int i = threadIdx.x; i < CIN * H; i += blockDim.x) Wl[i] = Win[i];
    __syncthreads();
    const int lane = threadIdx.x & 63;
    const int wpb = blockDim.x >> 6;
    int w = blockIdx.x * wpb + (threadIdx.x >> 6);
    const int wstride = gridDim.x * wpb;
    const float bv = bin[lane];
    for (int n = w; n < N; n += wstride) {
        float in = (lane < CIN) ? x[n * CIN + lane] : 0.f;
        float acc = bv;
        #pragma unroll
        for (int k = 0; k < CIN; ++k)
            acc += __shfl(in, k) * Wl[k * H + lane];
        x0[n * H + lane] = acc;
    }
}

// ---------------- CSR build ----------------
extern "C" __global__ void k_hist(const int* __restrict__ dst,
    unsigned* __restrict__ deg, int E)
{
    int i = blockIdx.x * blockDim.x + threadIdx.x;
    const int st = gridDim.x * blockDim.x;
    for (; i < E; i += st) atomicAdd(&deg[dst[i]], 1u);
}

extern "C" __global__ void k_scan1(const unsigned* __restrict__ deg,
    unsigned* __restrict__ indptr, unsigned* __restrict__ bsum, int N)
{
    __shared__ unsigned s[256];
    const int tid = threadIdx.x;
    const int base = blockIdx.x * 1024 + tid * 4;
    unsigned d[4];
    #pragma unroll
    for (int j = 0; j < 4; ++j) d[j] = (base + j < N) ? deg[base + j] : 0u;
    unsigned t = d[0] + d[1] + d[2] + d[3];
    s[tid] = t;
    __syncthreads();
    for (int o = 1; o < 256; o <<= 1) {
        unsigned v = (tid >= o) ? s[tid - o] : 0u;
        __syncthreads();
        s[tid] += v;
        __syncthreads();
    }
    unsigned run = (tid == 0) ? 0u : s[tid - 1];
    if (tid == 255) bsum[blockIdx.x] = s[255];
    #pragma unroll
    for (int j = 0; j < 4; ++j) {
        if (base + j < N) indptr[base + j] = run;
        run += d[j];
    }
}

extern "C" __global__ void k_scan2(unsigned* bsum, int nb)
{
    if (threadIdx.x == 0) {
        unsigned run = 0;
        for (int i = 0; i < nb; ++i) { unsigned v = bsum[i]; bsum[i] = run; run += v; }
    }
}

extern "C" __global__ void k_scan3(unsigned* __restrict__ indptr,
    const unsigned* __restrict__ bsum, unsigned* __restrict__ cursor, int N)
{
    const int base = blockIdx.x * 1024 + threadIdx.x * 4;
    const unsigned boff = bsum[blockIdx.x];
    #pragma unroll
    for (int j = 0; j < 4; ++j) {
        const int idx = base + j;
        if (idx < N) {
            const unsigned v = indptr[idx] + boff;
            indptr[idx] = v;
            cursor[idx] = v;
        }
    }
}

extern "C" __global__ void k_csr(const int* __restrict__ src,
    const int* __restrict__ dst, unsigned* __restrict__ cursor,
    int* __restrict__ esrc, int E)
{
    int i = blockIdx.x * blockDim.x + threadIdx.x;
    const int st = gridDim.x * blockDim.x;
    for (; i < E; i += st) {
        const int d = dst[i];
        const unsigned pos = atomicAdd(&cursor[d], 1u);
        esrc[pos] = src[i];
    }
}

// ------------- fused: aggregate + (1+eps)x + GEMM1 + BN stats -------------
extern "C" __global__ void __launch_bounds__(256) k_agg_gemm1(
    const float* __restrict__ x0, const int* __restrict__ esrc,
    const unsigned* __restrict__ indptr, const unsigned* __restrict__ deg,
    const float* __restrict__ W1, const float* __restrict__ b1,
    const float* __restrict__ epsp, float* __restrict__ h1,
    double* __restrict__ gsum, double* __restrict__ gsq, int N)
{
    __shared__ float Wl[H * TWOH];        // 32 KB
    __shared__ float ss[TWOH], sq[TWOH];  // 1 KB
    for (int i = threadIdx.x; i < H * TWOH; i += blockDim.x) Wl[i] = W1[i];
    if (threadIdx.x < TWOH) { ss[threadIdx.x] = 0.f; sq[threadIdx.x] = 0.f; }
    __syncthreads();
    const int lane = threadIdx.x & 63;
    const int wpb = blockDim.x >> 6;
    int w = blockIdx.x * wpb + (threadIdx.x >> 6);
    const int wstride = gridDim.x * wpb;
    const float ep = 1.f + epsp[0];
    const float b0 = b1[lane], bb = b1[H + lane];
    float s0 = 0.f, s1 = 0.f, q0 = 0.f, q1 = 0.f;
    for (int n = w; n < N; n += wstride) {
        const unsigned st0 = indptr[n];
        const unsigned cnt = deg[n];
        float acc = 0.f;
        unsigned e = 0;
        for (; e + 4 <= cnt; e += 4) {
            const int i0 = esrc[st0 + e];
            const int i1 = esrc[st0 + e + 1];
            const int i2 = esrc[st0 + e + 2];
            const int i3 = esrc[st0 + e + 3];
            const float v0 = x0[(size_t)i0 * H + lane];
            const float v1 = x0[(size_t)i1 * H + lane];
            const float v2 = x0[(size_t)i2 * H + lane];
            const float v3 = x0[(size_t)i3 * H + lane];
            acc += fmaxf(v0, 0.f) + fmaxf(v1, 0.f) + fmaxf(v2, 0.f) + fmaxf(v3, 0.f);
        }
        for (; e < cnt; ++e) {
            const float v = x0[(size_t)esrc[st0 + e] * H + lane];
            acc += fmaxf(v, 0.f);
        }
        const float h = ep * x0[(size_t)n * H + lane] + acc;
        float c0 = b0, c1 = bb;
        #pragma unroll
        for (int k = 0; k < H; ++k) {
            const float a = __shfl(h, k);
            c0 += a * Wl[k * TWOH + lane];
            c1 += a * Wl[k * TWOH + H + lane];
        }
        h1[(size_t)n * TWOH + lane] = c0;
        h1[(size_t)n * TWOH + H + lane] = c1;
        s0 += c0; s1 += c1; q0 += c0 * c0; q1 += c1 * c1;
    }
    atomicAdd(&ss[lane], s0); atomicAdd(&ss[H + lane], s1);
    atomicAdd(&sq[lane], q0); atomicAdd(&sq[H + lane], q1);
    __syncthreads();
    if (threadIdx.x < TWOH) {
        atomicAdd(&gsum[threadIdx.x], (double)ss[threadIdx.x]);
        atomicAdd(&gsq[threadIdx.x], (double)sq[threadIdx.x]);
    }
}

// ---------------- BN finalize: scale/shift ----------------
extern "C" __global__ void k_bnfin(const double* __restrict__ gsum,
    const double* __restrict__ gsq, const float* __restrict__ gamma,
    const float* __restrict__ beta, float* __restrict__ scsh, int N)
{
    const int j = threadIdx.x;
    if (j < TWOH) {
        const double mu = gsum[j] / N;
        const double var = gsq[j] / N - mu * mu;
        const float sc = gamma[j] * rsqrtf(fmaxf((float)var, 0.f) + 1e-5f);
        scsh[j] = sc;
        scsh[TWOH + j] = beta[j] - (float)mu * sc;
    }
}

// ------------- fused: BN apply + ReLU + GEMM2 + residual -------------
extern "C" __global__ void __launch_bounds__(256) k_gemm2(
    const float* __restrict__ h1, const float* __restrict__ scsh,
    const float* __restrict__ W2, const float* __restrict__ b2,
    float* __restrict__ x0, int N)
{
    __shared__ float Wl[TWOH * H];  // 32 KB
    __shared__ float sc[2 * TWOH];
    for (int i = threadIdx.x; i < TWOH * H; i += blockDim.x) Wl[i] = W2[i];
    for (int i = threadIdx.x; i < 2 * TWOH; i += blockDim.x) sc[i] = scsh[i];
    __syncthreads();
    const int lane = threadIdx.x & 63;
    const int wpb = blockDim.x >> 6;
    int w = blockIdx.x * wpb + (threadIdx.x >> 6);
    const int wstride = gridDim.x * wpb;
    const float bv = b2[lane];
    const float sc0 = sc[lane], sh0 = sc[TWOH + lane];
    const float sc1 = sc[H + lane], sh1 = sc[TWOH + H + lane];
    for (int n = w; n < N; n += wstride) {
        const float y0 = fmaxf(h1[(size_t)n * TWOH + lane] * sc0 + sh0, 0.f);
        const float y1 = fmaxf(h1[(size_t)n * TWOH + H + lane] * sc1 + sh1, 0.f);
        float acc = bv;
        #pragma unroll
        for (int k = 0; k < H; ++k)
            acc += __shfl(y0, k) * Wl[k * H + lane];
        #pragma unroll
        for (int k = 0; k < H; ++k)
            acc += __shfl(y1, k) * Wl[(H + k) * H + lane];
        x0[(size_t)n * H + lane] += acc;
    }
}

// ---------------- pooling + output ----------------
extern "C" __global__ void k_initout(const float* __restrict__ bout,
    float* __restrict__ out)
{
    if (threadIdx.x < NGRAPH) out[threadIdx.x] = bout[0];
}

extern "C" __global__ void __launch_bounds__(256) k_pool(
    const float* __restrict__ x0, const int* __restrict__ batch,
    const float* __restrict__ Wout, float* __restrict__ out, int N)
{
    __shared__ float pl[NGRAPH];
    if (threadIdx.x < NGRAPH) pl[threadIdx.x] = 0.f;
    __syncthreads();
    const int lane = threadIdx.x & 63;
    const int wpb = blockDim.x >> 6;
    int w = blockIdx.x * wpb + (threadIdx.x >> 6);
    const int wstride = gridDim.x * wpb;
    const float wv = Wout[lane];
    for (int n = w; n < N; n += wstride) {
        float v = x0[(size_t)n * H + lane] * wv;
        #pragma unroll
        for (int o = 32; o > 0; o >>= 1) v += __shfl_down(v, o);
        if (lane == 0) atomicAdd(&pl[batch[n]], v);
    }
    __syncthreads();
    if (threadIdx.x < NGRAPH) {
        const float v = pl[threadIdx.x];
        if (v != 0.f) atomicAdd(&out[threadIdx.x], v);
    }
}

// ---------------- host driver ----------------
extern "C" void kernel_launch(void* const* d_in, const int* in_sizes, int n_in,
                              void* d_out, int out_size, void* d_ws, size_t ws_size,
                              hipStream_t stream)
{
    const float* x     = (const float*)d_in[0];
    const int*   ei    = (const int*)d_in[1];   // int32 per harness conversion
    const int*   batch = (const int*)d_in[2];   // int32 per harness conversion
    const float* Win   = (const float*)d_in[3];
    const float* bin   = (const float*)d_in[4];
    const float* W1s   = (const float*)d_in[5];
    const float* b1s   = (const float*)d_in[6];
    const float* gam   = (const float*)d_in[7];
    const float* bet   = (const float*)d_in[8];
    const float* W2s   = (const float*)d_in[9];
    const float* b2s   = (const float*)d_in[10];
    const float* epss  = (const float*)d_in[11];
    const float* Wout  = (const float*)d_in[12];
    const float* bout  = (const float*)d_in[13];

    const int N = in_sizes[0] / CIN;
    const int E = in_sizes[1] / 2;
    const int L = in_sizes[11];
    const int* src = ei;
    const int* dst = ei + E;

    // workspace layout
    char* ws = (char*)d_ws;
    size_t off = 0;
    auto take = [&](size_t bytes) {
        void* p = ws + off;
        off += (bytes + 255) & ~(size_t)255;
        return p;
    };
    float*    x0     = (float*)take((size_t)N * H * 4);
    float*    h1     = (float*)take((size_t)N * TWOH * 4);
    unsigned* deg    = (unsigned*)take((size_t)N * 4);
    unsigned* indptr = (unsigned*)take((size_t)N * 4);
    unsigned* cursor = (unsigned*)take((size_t)N * 4);
    int*      esrc   = (int*)take((size_t)E * 4);
    unsigned* bsum   = (unsigned*)take(4096);
    double*   gsum   = (double*)take(TWOH * 8 * 2); // gsum + gsq contiguous
    double*   gsq    = gsum + TWOH;
    float*    scsh   = (float*)take(2 * TWOH * 4);
    (void)ws_size; (void)n_in; (void)out_size;

    hipMemsetAsync(deg, 0, (size_t)N * 4, stream);
    k_input_gemm<<<1024, 256, 0, stream>>>(x, Win, bin, x0, N);
    k_hist<<<2048, 256, 0, stream>>>(dst, deg, E);
    const int nb = (N + 1023) / 1024;
    k_scan1<<<nb, 256, 0, stream>>>(deg, indptr, bsum, N);
    k_scan2<<<1, 64, 0, stream>>>(bsum, nb);
    k_scan3<<<nb, 256, 0, stream>>>(indptr, bsum, cursor, N);
    k_csr<<<2048, 256, 0, stream>>>(src, dst, cursor, esrc, E);

    for (int l = 0; l < L; ++l) {
        hipMemsetAsync(gsum, 0, TWOH * 8 * 2, stream);
        k_agg_gemm1<<<2048, 256, 0, stream>>>(x0, esrc, indptr, deg,
            W1s + (size_t)l * H * TWOH, b1s + (size_t)l * TWOH, epss + l,
            h1, gsum, gsq, N);
        k_bnfin<<<1, 128, 0, stream>>>(gsum, gsq, gam + (size_t)l * TWOH,
            bet + (size_t)l * TWOH, scsh, N);
        k_gemm2<<<2048, 256, 0, stream>>>(h1, scsh,
            W2s + (size_t)l * TWOH * H, b2s + (size_t)l * H, x0, N);
    }

    k_initout<<<1, 64, 0, stream>>>(bout, (float*)d_out);
    k_pool<<<512, 256, 0, stream>>>(x0, batch, Wout, (float*)d_out, N);
}